// Round 2
// baseline (82.386 us; speedup 1.0000x reference)
//
#include <hip/hip_runtime.h>
#include <math.h>

#define HID 2880
#define NE  128
#define BK  32              // k per chunk (1 x 32)
#define TOKB 32
#define NCH 90              // total chunks; 3 groups x 30
#define HN  30              // chunks per k-group
#define PSTR 129

typedef _Float16 half4v __attribute__((ext_vector_type(4)));
typedef _Float16 half8v __attribute__((ext_vector_type(8)));
typedef float    f32x4v __attribute__((ext_vector_type(4)));

// ---------------- prep: split W fp32 -> f16 hi/lo, [kt 45][sub 2][e 128][k 32] ------
// (chunk c (BK=32) = halves offset c*4096: [c][e 128][k 32])
__global__ __launch_bounds__(256)
void prep_w(const float* __restrict__ W, _Float16* __restrict__ whi,
            _Float16* __restrict__ wlo)
{
    const int e = blockIdx.x;
    for (int j = 0; j < 12; ++j) {
        const int k = j * 256 + threadIdx.x;
        if (k >= HID) break;
        const float v = W[(size_t)e * HID + k];
        const _Float16 h = (_Float16)v;
        const _Float16 l = (_Float16)(v - (float)h);
        const size_t idx = (size_t)(k >> 6) * 8192 + ((k >> 5) & 1) * 4096
                         + e * 32 + (k & 31);
        whi[idx] = h;
        wlo[idx] = l;
    }
}

// asm-forced 16B global load: regs cannot be collapsed/sunk; order = issue order.
#define GLOAD(dst, ptr) \
    asm volatile("global_load_dwordx4 %0, %1, off" : "=v"(dst) : "v"(ptr))
#define GLOAD_O1024(dst, ptr) \
    asm volatile("global_load_dwordx4 %0, %1, off offset:1024" : "=v"(dst) : "v"(ptr))

// ---------------- fused: 12-wave 3-way k-split, TOKB=32/BK=32, 2 blocks/CU ----------
// grid T/32 = 512 blocks (2/CU for cross-block phase overlap: r1's null result on
// the conflict fix proved the loop is serialization-bound, not pipe-bound).
// 768 thr (12 waves, 6/SIMD across the two blocks). ks = wv>>2 (k-third, 30
// chunks), wq = wv&3 -> experts [wq*32,+32) x 32 tok. W sets shrunk to 4 half8v
// (BK=32) so VGPR <= 80 => 6 waves/SIMD co-residency. Step issues A(1)+W(4);
// vmcnt(5) retires W(i) before MFMA; vmcnt(4) after MFMA retires A(i+1) for
// CONVA, keeping W(i+1) in flight across the lgkm-only barrier.
//
// A-tile LDS swizzle (r1): kbyte ^= ((tok>>1)&3)<<4 on both write and read side.
__global__ __launch_bounds__(768, 6)
void fused_router(const float* __restrict__ A, const _Float16* __restrict__ whi,
                  const _Float16* __restrict__ wlo, const float* __restrict__ bias,
                  float* __restrict__ scores, float* __restrict__ idxOut,
                  float* __restrict__ counts)
{
    // staging: [ks3][buf2][h2][32 tok][32 k] halves = 24576 B; epilogue overlay
    // needs 41472 B (P1 16512 + P2 16512 + cval 4224 + cidx 4224)
    __shared__ __align__(16) char smem[41472];
    __shared__ float sval[TOKB][4];
    __shared__ int   sidx[TOKB][4];
    __shared__ int   hist[NE];

#define SA(ks, buf, h) \
    (smem + (ks) * 8192 + (((buf) * 2 + (h)) * 2048))

#define SWZ(tok) ((((tok) >> 1) & 3) << 4)

    const int tid  = threadIdx.x;
    const int lane = tid & 63;
    const int wv   = __builtin_amdgcn_readfirstlane(tid >> 6);   // 0..11
    const int ks   = wv >> 2;        // k-third 0..2
    const int wq   = wv & 3;         // expert group 0..3
    const int lg   = lane >> 4;      // k-quarter 0..3
    const int lr   = lane & 15;
    const int tokBase = blockIdx.x * TOKB;
    const int hbeg = ks * HN;

    // W per-lane fragment base (m=0): e = wq*32 + lr, k-off lg*8.
    // m=1 adds 16 experts * 32 halves = 1024 B -> offset:1024 immediate.
    const _Float16* wHp0 = whi + (size_t)((wq * 32 + lr) * 32 + lg * 8);
    const _Float16* wLp0 = wlo + (size_t)((wq * 32 + lr) * 32 + lg * 8);

    // A producer: per ks-group 256 threads stage 32 tok x 8 f4-slots; 1/thread
    const int gid = tid & 255;
    const int ptok = gid >> 3, pq = gid & 7;
    const float* aSrc = A + (size_t)(tokBase + ptok) * HID + pq * 4;
    const int aWr = ptok * 64 + ((pq * 8) ^ SWZ(ptok));   // swizzled byte off

    // A consumer byte offsets: token n*16+lr, k-quarter lg (same swizzle)
    int aRd[2];
#pragma unroll
    for (int n = 0; n < 2; ++n) {
        const int tok = n * 16 + lr;
        aRd[n] = tok * 64 + ((lg * 16) ^ SWZ(tok));
    }

    float4 aA;
#define AISSUE(c) GLOAD(aA, aSrc + (size_t)(c) * BK)

    // W set: [m*2 + hl] -> 4 half8v = 16 VGPR forced
#define WISSUE(SET, c) do {                                                    \
    const _Float16* hp_ = wHp0 + (size_t)(c) * 4096;                           \
    const _Float16* lp_ = wLp0 + (size_t)(c) * 4096;                           \
    GLOAD(SET[0], hp_);                                                        \
    GLOAD(SET[1], lp_);                                                        \
    GLOAD_O1024(SET[2], hp_);                                                  \
    GLOAD_O1024(SET[3], lp_);                                                  \
} while (0)

    auto CONVA = [&](int buf) {
        const float4 v = aA;
        const _Float16 h0 = (_Float16)v.x, h1 = (_Float16)v.y,
                       h2 = (_Float16)v.z, h3 = (_Float16)v.w;
        const half4v hh = {h0, h1, h2, h3};
        const half4v ll = {(_Float16)(v.x - (float)h0),
                           (_Float16)(v.y - (float)h1),
                           (_Float16)(v.z - (float)h2),
                           (_Float16)(v.w - (float)h3)};
        *reinterpret_cast<half4v*>(SA(ks, buf, 0) + aWr) = hh;
        *reinterpret_cast<half4v*>(SA(ks, buf, 1) + aWr) = ll;
    };

    f32x4v acc[2][2];
#pragma unroll
    for (int m = 0; m < 2; ++m)
#pragma unroll
        for (int n = 0; n < 2; ++n) acc[m][n] = (f32x4v)0.f;

    half8v wA[4], wB[4];

#define STEP(i, SU, SF) do {                                                   \
    if ((i) + 1 < HN) { AISSUE(hbeg + (i) + 1); WISSUE(SF, hbeg + (i) + 1); }  \
    __builtin_amdgcn_sched_barrier(0);                                         \
    if ((i) + 1 < HN) asm volatile("s_waitcnt vmcnt(5)" ::: "memory");         \
    else              asm volatile("s_waitcnt vmcnt(0)" ::: "memory");         \
    __builtin_amdgcn_sched_barrier(0);                                         \
    const int buf_ = (i) & 1;                                                  \
    _Pragma("unroll")                                                          \
    for (int n = 0; n < 2; ++n) {                                              \
        const half8v ah = *reinterpret_cast<const half8v*>(                    \
            SA(ks, buf_, 0) + aRd[n]);                                         \
        const half8v al = *reinterpret_cast<const half8v*>(                    \
            SA(ks, buf_, 1) + aRd[n]);                                         \
        _Pragma("unroll")                                                      \
        for (int m = 0; m < 2; ++m) {                                          \
            acc[m][n] = __builtin_amdgcn_mfma_f32_16x16x32_f16(                \
                SU[m * 2 + 0], ah, acc[m][n], 0, 0, 0);                        \
            acc[m][n] = __builtin_amdgcn_mfma_f32_16x16x32_f16(                \
                SU[m * 2 + 1], ah, acc[m][n], 0, 0, 0);                        \
            acc[m][n] = __builtin_amdgcn_mfma_f32_16x16x32_f16(                \
                SU[m * 2 + 0], al, acc[m][n], 0, 0, 0);                        \
        }                                                                      \
    }                                                                          \
    if ((i) + 1 < HN) {                                                        \
        asm volatile("s_waitcnt vmcnt(4)" ::: "memory");                       \
        __builtin_amdgcn_sched_barrier(0);                                     \
        CONVA(((i) + 1) & 1);                                                  \
    }                                                                          \
    asm volatile("s_waitcnt lgkmcnt(0)" ::: "memory");                         \
    __builtin_amdgcn_sched_barrier(0);                                         \
    __builtin_amdgcn_s_barrier();                                              \
    __builtin_amdgcn_sched_barrier(0);                                         \
} while (0)

    // prologue: A(hbeg)[1] + W(hbeg)->wA[4]; vmcnt(4) retires A; publish buf0
    AISSUE(hbeg);
    WISSUE(wA, hbeg);
    asm volatile("s_waitcnt vmcnt(4)" ::: "memory");
    __builtin_amdgcn_sched_barrier(0);
    CONVA(0);
    asm volatile("s_waitcnt lgkmcnt(0)" ::: "memory");
    __builtin_amdgcn_sched_barrier(0);
    __builtin_amdgcn_s_barrier();
    __builtin_amdgcn_sched_barrier(0);

#pragma unroll 1
    for (int i = 0; i < HN; i += 2) {      // HN even: all steps in-loop
        STEP(i,     wA, wB);
        STEP(i + 1, wB, wA);
    }

    // ---------------- epilogue: deterministic 3-way reduction ----------------
    float* P1   = (float*)(smem);            // 32*129*4 = 16512 B (overlay)
    float* P2   = (float*)(smem + 16512);    // 16512 B
    float* cval = (float*)(smem + 33024);    // 32*33*4 = 4224 B
    int*   cidx = (int*)(smem + 37248);      // 4224 B

    if (tid < NE) hist[tid] = 0;

    // ks=1/2 partials -> LDS (staging dead after final barrier)
    if (ks == 1 || ks == 2) {
        float* P = (ks == 1) ? P1 : P2;
#pragma unroll
        for (int m = 0; m < 2; ++m)
#pragma unroll
            for (int n = 0; n < 2; ++n)
#pragma unroll
                for (int r = 0; r < 4; ++r) {
                    const int e = wq * 32 + m * 16 + lg * 4 + r;
                    const int t = n * 16 + lr;
                    P[t * PSTR + e] = acc[m][n][r];
                }
    }
    __syncthreads();

    // ks=0 combines in fixed order -> logits in P1
    if (ks == 0) {
#pragma unroll
        for (int m = 0; m < 2; ++m)
#pragma unroll
            for (int n = 0; n < 2; ++n)
#pragma unroll
                for (int r = 0; r < 4; ++r) {
                    const int e = wq * 32 + m * 16 + lg * 4 + r;
                    const int t = n * 16 + lr;
                    const int off = t * PSTR + e;
                    P1[off] = ((acc[m][n][r] + P1[off]) + P2[off]) + bias[e];
                }
    }
    __syncthreads();

    // top-4 candidates: 32 tok x 8 groups of 16 experts (threads 0..255)
    if (tid < 256) {
        const int t = tid & 31, g = tid >> 5;
        float v0 = -1e30f, v1 = -1e30f, v2 = -1e30f, v3 = -1e30f;
        int   i0 = 0, i1 = 0, i2 = 0, i3 = 0;
        const int e0 = g * 16;
#pragma unroll 4
        for (int i = 0; i < 16; ++i) {
            const int e = e0 + i;
            const float v = P1[t * PSTR + e];
            if (v > v3) {
                if (v > v2) {
                    v3 = v2; i3 = i2;
                    if (v > v1) {
                        v2 = v1; i2 = i1;
                        if (v > v0) { v1 = v0; i1 = i0; v0 = v; i0 = e; }
                        else        { v1 = v;  i1 = e; }
                    } else { v2 = v; i2 = e; }
                } else { v3 = v; i3 = e; }
            }
        }
        cval[t * 33 + g * 4 + 0] = v0; cidx[t * 33 + g * 4 + 0] = i0;
        cval[t * 33 + g * 4 + 1] = v1; cidx[t * 33 + g * 4 + 1] = i1;
        cval[t * 33 + g * 4 + 2] = v2; cidx[t * 33 + g * 4 + 2] = i2;
        cval[t * 33 + g * 4 + 3] = v3; cidx[t * 33 + g * 4 + 3] = i3;
    }
    __syncthreads();

    if (tid < TOKB) {
        const int t = tid;
        float m0 = -1e30f, m1 = -1e30f, m2 = -1e30f, m3 = -1e30f;
        int   j0 = 0, j1 = 0, j2 = 0, j3 = 0;
#pragma unroll
        for (int q = 0; q < 32; ++q) {   // group-major, ascending e within group
            const float v = cval[t * 33 + q];
            const int   e = cidx[t * 33 + q];
            if (v > m3) {
                if (v > m2) {
                    m3 = m2; j3 = j2;
                    if (v > m1) {
                        m2 = m1; j2 = j1;
                        if (v > m0) { m1 = m0; j1 = j0; m0 = v; j0 = e; }
                        else        { m1 = v;  j1 = e; }
                    } else { m2 = v; j2 = e; }
                } else { m3 = v; j3 = e; }
            }
        }
        const float x1 = expf(m1 - m0), x2 = expf(m2 - m0), x3 = expf(m3 - m0);
        const float inv = 1.f / (1.f + x1 + x2 + x3);
        sval[t][0] = inv;      sidx[t][0] = j0;
        sval[t][1] = x1 * inv; sidx[t][1] = j1;
        sval[t][2] = x2 * inv; sidx[t][2] = j2;
        sval[t][3] = x3 * inv; sidx[t][3] = j3;
        atomicAdd(&hist[j0], 1); atomicAdd(&hist[j1], 1);
        atomicAdd(&hist[j2], 1); atomicAdd(&hist[j3], 1);
    }
    __syncthreads();

    // dense score scatter: 32 tok x 128 exp = 4096 floats, coalesced
    const size_t sBase = (size_t)blockIdx.x * TOKB * NE;
#pragma unroll 3
    for (int it = 0; it < 6; ++it) {
        const int flat = it * 768 + tid;
        if (flat < TOKB * NE) {
            const int t = flat >> 7, e = flat & 127;
            float val = 0.f;
            val = (e == sidx[t][0]) ? sval[t][0] : val;
            val = (e == sidx[t][1]) ? sval[t][1] : val;
            val = (e == sidx[t][2]) ? sval[t][2] : val;
            val = (e == sidx[t][3]) ? sval[t][3] : val;
            scores[sBase + flat] = val;
        }
    }
    // indices as float32: 128 per block
    if (tid < TOKB * 4)
        idxOut[(size_t)blockIdx.x * TOKB * 4 + tid] =
            (float)sidx[tid >> 2][tid & 3];
    if (tid < NE) {
        const int c = hist[tid];
        if (c) atomicAdd(&counts[tid], (float)c);
    }
#undef SA
#undef SWZ
#undef AISSUE
#undef WISSUE
#undef STEP
}

extern "C" void kernel_launch(void* const* d_in, const int* in_sizes, int n_in,
                              void* d_out, int out_size, void* d_ws, size_t ws_size,
                              hipStream_t stream) {
    const float* A = (const float*)d_in[0];   // hidden_states [T, 2880]
    const float* W = (const float*)d_in[1];   // weight [128, 2880]
    const float* B = (const float*)d_in[2];   // bias [128]
    const int T = in_sizes[0] / HID;          // 16384

    float* out = (float*)d_out;
    float* scores = out;                          // [T,128]
    float* idxOut = out + (size_t)T * NE;         // [T,4] as float
    float* counts = idxOut + (size_t)T * 4;       // [128] as float

    _Float16* whi = (_Float16*)d_ws;              // [90][128][32] halves
    _Float16* wlo = whi + (size_t)NE * HID;

    hipMemsetAsync(counts, 0, NE * sizeof(float), stream);

    hipLaunchKernelGGL(prep_w, dim3(NE), dim3(256), 0, stream, W, whi, wlo);
    hipLaunchKernelGGL(fused_router, dim3(T / TOKB), dim3(768), 0, stream,
                       A, whi, wlo, B, scores, idxOut, counts);
}

// Round 3
// 66.831 us; speedup vs baseline: 1.2328x; 1.2328x over previous
//
#include <hip/hip_runtime.h>
#include <math.h>

#define HID 2880
#define NE  128
#define BK  32              // k per chunk
#define TOKB 64
#define NCHG 30             // chunks per ks-group (3 groups x 30 = 90)
#define PSTR 129

typedef _Float16 half8v __attribute__((ext_vector_type(8)));
typedef float    f32x4v __attribute__((ext_vector_type(4)));

// ---------------- prep: split W fp32 -> f16 hi/lo, [chunk 90][e 128][k 32] ------
__global__ __launch_bounds__(256)
void prep_w(const float* __restrict__ W, _Float16* __restrict__ whi,
            _Float16* __restrict__ wlo)
{
    const int e = blockIdx.x;
    for (int j = 0; j < 12; ++j) {
        const int k = j * 256 + threadIdx.x;
        if (k >= HID) break;
        const float v = W[(size_t)e * HID + k];
        const _Float16 h = (_Float16)v;
        const _Float16 l = (_Float16)(v - (float)h);
        const size_t idx = (size_t)(k >> 5) * 4096 + e * 32 + (k & 31);
        whi[idx] = h;
        wlo[idx] = l;
    }
}

// asm-forced 16B global load: regs cannot be collapsed/sunk; order = issue order.
#define GLOAD(dst, ptr) \
    asm volatile("global_load_dwordx4 %0, %1, off" : "=v"(dst) : "v"(ptr))
#define GLOAD_O1024(dst, ptr) \
    asm volatile("global_load_dwordx4 %0, %1, off offset:1024" : "=v"(dst) : "v"(ptr))

// ---------------- fused: 12-wave 3-way k-split, 3-chunk epochs over 6-slot ring ----
// grid 256 (1 block/CU), 768 thr (12 waves, 3/SIMD). ks = wv>>2 (k-third, 30
// chunks of 32k), wq = wv&3 -> experts [wq*32,+32) x 64 tok.
// R2 lesson: ~3k cy fixed cost per barrier-step; so sync once per 3 chunks:
// epoch e consumes chunks 3e..3e+2 from ring slots (written last epoch), issues
// A-group(e+1) global loads at epoch start (full-epoch latency cover), W rolls
// chunk-by-chunk in 2 register sets with counted vmcnt (never 0 mid-loop;
// W(b+3) stays in flight across the barrier), CONVA writes group e+1 at epoch
// end, then ONE lgkmcnt(0)+s_barrier. 11 barriers total vs R1's 16.
__global__ __launch_bounds__(768, 3)
void fused_router(const float* __restrict__ A, const _Float16* __restrict__ whi,
                  const _Float16* __restrict__ wlo, const float* __restrict__ bias,
                  float* __restrict__ scores, float* __restrict__ idxOut,
                  float* __restrict__ counts)
{
    // ring: [ks 3][slot 6][h 2][64 tok][32 k f16] = 3*6*8192 = 147456 B
    __shared__ __align__(16) char smem[147456];
    __shared__ float sval[TOKB][4];
    __shared__ int   sidx[TOKB][4];
    __shared__ int   hist[NE];

#define SWZ(tok) ((((tok) >> 1) & 3) << 4)

    const int tid  = threadIdx.x;
    const int lane = tid & 63;
    const int wv   = __builtin_amdgcn_readfirstlane(tid >> 6);   // 0..11
    const int ks   = wv >> 2;        // k-third 0..2
    const int wq   = wv & 3;         // expert group 0..3
    const int lg   = lane >> 4;      // k-quarter 0..3
    const int lr   = lane & 15;
    const int tokBase = blockIdx.x * TOKB;
    const int hbeg = ks * NCHG;      // first global chunk of this k-third

    // W per-lane fragment base (m=0): e = wq*32 + lr, k-off lg*8.
    // m=1 adds 16 experts * 32 halves = 1024 B -> offset:1024 immediate.
    const _Float16* wHp0 = whi + (size_t)((wq * 32 + lr) * 32 + lg * 8);
    const _Float16* wLp0 = wlo + (size_t)((wq * 32 + lr) * 32 + lg * 8);

    // A producer: ks-group's 256 threads stage 64 tok x 32 k per chunk;
    // thread -> (tok, 8-float k-part): 2 dwordx4 per chunk.
    const int gid   = tid & 255;
    const int ptok  = gid >> 2;
    const int ppart = gid & 3;
    const float* aSrc = A + (size_t)(tokBase + ptok) * HID + ppart * 8;
    const int aWr = ptok * 64 + ((ppart * 16) ^ SWZ(ptok));   // swizzled byte off

    // A consumer byte offsets: token n*16+lr, k-quarter lg (same swizzle)
    int aRd[4];
#pragma unroll
    for (int n = 0; n < 4; ++n) {
        const int tok = n * 16 + lr;
        aRd[n] = tok * 64 + ((lg * 16) ^ SWZ(tok));
    }

    // W set: [m*2 + hl] -> 4 half8v = 16 VGPR forced
#define WISSUE(SET, ch) do {                                                   \
    const _Float16* hp_ = wHp0 + (size_t)(ch) * 4096;                          \
    const _Float16* lp_ = wLp0 + (size_t)(ch) * 4096;                          \
    GLOAD(SET[0], hp_);                                                        \
    GLOAD(SET[1], lp_);                                                        \
    GLOAD_O1024(SET[2], hp_);                                                  \
    GLOAD_O1024(SET[3], lp_);                                                  \
} while (0)

    // convert one chunk's A regs (2 float4) -> hi/lo half8, write ring slot
#define CONVA1(AX, AY, SLOT) do {                                              \
    const _Float16 h0=(_Float16)AX.x, h1=(_Float16)AX.y,                       \
                   h2=(_Float16)AX.z, h3=(_Float16)AX.w;                       \
    const _Float16 h4=(_Float16)AY.x, h5=(_Float16)AY.y,                       \
                   h6=(_Float16)AY.z, h7=(_Float16)AY.w;                       \
    const half8v hh = {h0,h1,h2,h3,h4,h5,h6,h7};                               \
    const half8v ll = {(_Float16)(AX.x-(float)h0),(_Float16)(AX.y-(float)h1),  \
                       (_Float16)(AX.z-(float)h2),(_Float16)(AX.w-(float)h3),  \
                       (_Float16)(AY.x-(float)h4),(_Float16)(AY.y-(float)h5),  \
                       (_Float16)(AY.z-(float)h6),(_Float16)(AY.w-(float)h7)}; \
    char* wb_ = smem + ks * 49152 + (SLOT) * 8192 + aWr;                       \
    *reinterpret_cast<half8v*>(wb_)        = hh;                               \
    *reinterpret_cast<half8v*>(wb_ + 4096) = ll;                               \
} while (0)

    // consume one chunk from ring slot with W register set
#define CCHUNK(SLOT, SET) do {                                                 \
    const char* b0_ = smem + ks * 49152 + (SLOT) * 8192;                       \
    _Pragma("unroll")                                                          \
    for (int n = 0; n < 4; ++n) {                                              \
        const half8v ah = *reinterpret_cast<const half8v*>(b0_ + aRd[n]);      \
        const half8v al = *reinterpret_cast<const half8v*>(b0_ + 4096 + aRd[n]);\
        _Pragma("unroll")                                                      \
        for (int m = 0; m < 2; ++m) {                                          \
            acc[m][n] = __builtin_amdgcn_mfma_f32_16x16x32_f16(                \
                SET[m * 2 + 0], ah, acc[m][n], 0, 0, 0);                       \
            acc[m][n] = __builtin_amdgcn_mfma_f32_16x16x32_f16(                \
                SET[m * 2 + 1], ah, acc[m][n], 0, 0, 0);                       \
            acc[m][n] = __builtin_amdgcn_mfma_f32_16x16x32_f16(                \
                SET[m * 2 + 0], al, acc[m][n], 0, 0, 0);                       \
        }                                                                      \
    }                                                                          \
} while (0)

#define VMC(n) do {                                                            \
    asm volatile("s_waitcnt vmcnt(" #n ")" ::: "memory");                      \
    __builtin_amdgcn_sched_barrier(0);                                         \
} while (0)

    f32x4v acc[2][4];
#pragma unroll
    for (int m = 0; m < 2; ++m)
#pragma unroll
        for (int n = 0; n < 4; ++n) acc[m][n] = (f32x4v)0.f;

    half8v wS0[4], wS1[4];
    float4 aR0, aR1, aR2, aR3, aR4, aR5;

    // stage A-group (3 chunks starting at group-local chunk B_) into aR0..aR5
#define ASTAGE(B_) do {                                                        \
    const float* p_ = aSrc + (size_t)(hbeg + (B_)) * BK;                       \
    GLOAD(aR0, p_);      GLOAD(aR1, p_ + 4);                                   \
    GLOAD(aR2, p_ + 32); GLOAD(aR3, p_ + 36);                                  \
    GLOAD(aR4, p_ + 64); GLOAD(aR5, p_ + 68);                                  \
} while (0)

    // EPOCH(E, SU0, SU1, CS, PS, STAGE, FINAL, C0VM):
    //   consumes chunks 3E..3E+2 (slots CS..CS+2), sets SU0/SU1/SU0;
    //   STAGE: issues A-group(E+1) + CONVA into PS..PS+2 + barrier.
#define EPOCH(E, SU0, SU1, CS, PS, STAGE, FINAL, C0VM) do {                    \
    const int b_ = 3 * (E);                                                    \
    if (STAGE) ASTAGE(b_ + 3);                                                 \
    __builtin_amdgcn_sched_barrier(0);                                         \
    WISSUE(SU1, hbeg + b_ + 1);                                                \
    __builtin_amdgcn_sched_barrier(0);                                         \
    VMC(C0VM);                                                                 \
    CCHUNK((CS) + 0, SU0);                                                     \
    WISSUE(SU0, hbeg + b_ + 2);                                                \
    __builtin_amdgcn_sched_barrier(0);                                         \
    VMC(4);                                                                    \
    CCHUNK((CS) + 1, SU1);                                                     \
    if (!(FINAL)) { WISSUE(SU1, hbeg + b_ + 3); }                              \
    __builtin_amdgcn_sched_barrier(0);                                         \
    if (FINAL) VMC(0); else VMC(4);                                            \
    CCHUNK((CS) + 2, SU0);                                                     \
    if (STAGE) {                                                               \
        VMC(4);                                                                \
        CONVA1(aR0, aR1, (PS) + 0);                                            \
        CONVA1(aR2, aR3, (PS) + 1);                                            \
        CONVA1(aR4, aR5, (PS) + 2);                                            \
        asm volatile("s_waitcnt lgkmcnt(0)" ::: "memory");                     \
        __builtin_amdgcn_sched_barrier(0);                                     \
        __builtin_amdgcn_s_barrier();                                          \
        __builtin_amdgcn_sched_barrier(0);                                     \
    }                                                                          \
} while (0)

    // prologue: A-group(0) + W(0)->wS0; retire A (vmcnt(4) keeps W(0) in
    // flight); CONVA chunks 0..2 into slots 0..2; publish.
    ASTAGE(0);
    WISSUE(wS0, hbeg + 0);
    VMC(4);
    CONVA1(aR0, aR1, 0);
    CONVA1(aR2, aR3, 1);
    CONVA1(aR4, aR5, 2);
    asm volatile("s_waitcnt lgkmcnt(0)" ::: "memory");
    __builtin_amdgcn_sched_barrier(0);
    __builtin_amdgcn_s_barrier();
    __builtin_amdgcn_sched_barrier(0);

    // epochs 0..7 (paired even/odd), 8 (even, staging), 9 (odd, final)
#pragma unroll 1
    for (int e = 0; e < 8; e += 2) {
        EPOCH(e,     wS0, wS1, 0, 3, 1, 0, 10);
        EPOCH(e + 1, wS1, wS0, 3, 0, 1, 0, 10);
    }
    EPOCH(8, wS0, wS1, 0, 3, 1, 0, 10);
    EPOCH(9, wS1, wS0, 3, 0, 0, 1, 4);

    __syncthreads();   // all ring reads done before epilogue overlay

    // ---------------- epilogue: deterministic 3-way reduction ----------------
    float* P1   = (float*)(smem);            // 64*129*4 = 33024 B (overlay)
    float* P2   = (float*)(smem + 33024);    // 33024 B
    float* cval = (float*)(smem + 66048);    // 64*33*4 = 8448 B
    int*   cidx = (int*)(smem + 74496);      // 8448 B

    if (tid < NE) hist[tid] = 0;

    // ks=1/2 partials -> LDS
    if (ks == 1 || ks == 2) {
        float* P = (ks == 1) ? P1 : P2;
#pragma unroll
        for (int m = 0; m < 2; ++m)
#pragma unroll
            for (int n = 0; n < 4; ++n)
#pragma unroll
                for (int r = 0; r < 4; ++r) {
                    const int e = wq * 32 + m * 16 + lg * 4 + r;
                    const int t = n * 16 + lr;
                    P[t * PSTR + e] = acc[m][n][r];
                }
    }
    __syncthreads();

    // ks=0 combines in fixed order -> logits in P1
    if (ks == 0) {
#pragma unroll
        for (int m = 0; m < 2; ++m)
#pragma unroll
            for (int n = 0; n < 4; ++n)
#pragma unroll
                for (int r = 0; r < 4; ++r) {
                    const int e = wq * 32 + m * 16 + lg * 4 + r;
                    const int t = n * 16 + lr;
                    const int off = t * PSTR + e;
                    P1[off] = ((acc[m][n][r] + P1[off]) + P2[off]) + bias[e];
                }
    }
    __syncthreads();

    // top-4 candidates: 64 tok x 8 groups of 16 experts (threads 0..511)
    if (tid < 512) {
        const int t = tid & 63, g = tid >> 6;
        float v0 = -1e30f, v1 = -1e30f, v2 = -1e30f, v3 = -1e30f;
        int   i0 = 0, i1 = 0, i2 = 0, i3 = 0;
        const int e0 = g * 16;
#pragma unroll 4
        for (int i = 0; i < 16; ++i) {
            const int e = e0 + i;
            const float v = P1[t * PSTR + e];
            if (v > v3) {
                if (v > v2) {
                    v3 = v2; i3 = i2;
                    if (v > v1) {
                        v2 = v1; i2 = i1;
                        if (v > v0) { v1 = v0; i1 = i0; v0 = v; i0 = e; }
                        else        { v1 = v;  i1 = e; }
                    } else { v2 = v; i2 = e; }
                } else { v3 = v; i3 = e; }
            }
        }
        cval[t * 33 + g * 4 + 0] = v0; cidx[t * 33 + g * 4 + 0] = i0;
        cval[t * 33 + g * 4 + 1] = v1; cidx[t * 33 + g * 4 + 1] = i1;
        cval[t * 33 + g * 4 + 2] = v2; cidx[t * 33 + g * 4 + 2] = i2;
        cval[t * 33 + g * 4 + 3] = v3; cidx[t * 33 + g * 4 + 3] = i3;
    }
    __syncthreads();

    if (tid < TOKB) {
        const int t = tid;
        float m0 = -1e30f, m1 = -1e30f, m2 = -1e30f, m3 = -1e30f;
        int   j0 = 0, j1 = 0, j2 = 0, j3 = 0;
#pragma unroll
        for (int q = 0; q < 32; ++q) {   // group-major, ascending e within group
            const float v = cval[t * 33 + q];
            const int   e = cidx[t * 33 + q];
            if (v > m3) {
                if (v > m2) {
                    m3 = m2; j3 = j2;
                    if (v > m1) {
                        m2 = m1; j2 = j1;
                        if (v > m0) { m1 = m0; j1 = j0; m0 = v; j0 = e; }
                        else        { m1 = v;  j1 = e; }
                    } else { m2 = v; j2 = e; }
                } else { m3 = v; j3 = e; }
            }
        }
        const float x1 = expf(m1 - m0), x2 = expf(m2 - m0), x3 = expf(m3 - m0);
        const float inv = 1.f / (1.f + x1 + x2 + x3);
        sval[t][0] = inv;      sidx[t][0] = j0;
        sval[t][1] = x1 * inv; sidx[t][1] = j1;
        sval[t][2] = x2 * inv; sidx[t][2] = j2;
        sval[t][3] = x3 * inv; sidx[t][3] = j3;
        atomicAdd(&hist[j0], 1); atomicAdd(&hist[j1], 1);
        atomicAdd(&hist[j2], 1); atomicAdd(&hist[j3], 1);
    }
    __syncthreads();

    // dense score scatter: 64 tok x 128 exp = 8192 floats, coalesced
    const size_t sBase = (size_t)blockIdx.x * TOKB * NE;
#pragma unroll 4
    for (int it = 0; it < 11; ++it) {
        const int flat = it * 768 + tid;
        if (flat < TOKB * NE) {
            const int t = flat >> 7, e = flat & 127;
            float val = 0.f;
            val = (e == sidx[t][0]) ? sval[t][0] : val;
            val = (e == sidx[t][1]) ? sval[t][1] : val;
            val = (e == sidx[t][2]) ? sval[t][2] : val;
            val = (e == sidx[t][3]) ? sval[t][3] : val;
            scores[sBase + flat] = val;
        }
    }
    // indices as float32: 256 per block
    if (tid < TOKB * 4)
        idxOut[(size_t)blockIdx.x * TOKB * 4 + tid] =
            (float)sidx[tid >> 2][tid & 3];
    if (tid < NE) {
        const int c = hist[tid];
        if (c) atomicAdd(&counts[tid], (float)c);
    }
#undef SWZ
#undef WISSUE
#undef CONVA1
#undef CCHUNK
#undef VMC
#undef ASTAGE
#undef EPOCH
}

extern "C" void kernel_launch(void* const* d_in, const int* in_sizes, int n_in,
                              void* d_out, int out_size, void* d_ws, size_t ws_size,
                              hipStream_t stream) {
    const float* A = (const float*)d_in[0];   // hidden_states [T, 2880]
    const float* W = (const float*)d_in[1];   // weight [128, 2880]
    const float* B = (const float*)d_in[2];   // bias [128]
    const int T = in_sizes[0] / HID;          // 16384

    float* out = (float*)d_out;
    float* scores = out;                          // [T,128]
    float* idxOut = out + (size_t)T * NE;         // [T,4] as float
    float* counts = idxOut + (size_t)T * 4;       // [128] as float

    _Float16* whi = (_Float16*)d_ws;              // [90][128][32] halves
    _Float16* wlo = whi + (size_t)NE * HID;

    hipMemsetAsync(counts, 0, NE * sizeof(float), stream);

    hipLaunchKernelGGL(prep_w, dim3(NE), dim3(256), 0, stream, W, whi, wlo);
    hipLaunchKernelGGL(fused_router, dim3(T / TOKB), dim3(768), 0, stream,
                       A, whi, wlo, B, scores, idxOut, counts);
}

// Round 4
// 66.612 us; speedup vs baseline: 1.2368x; 1.0033x over previous
//
#include <hip/hip_runtime.h>
#include <math.h>

#define HID 2880
#define NE  128
#define BK  32              // k per chunk
#define TOKB 64
#define NCHG 30             // chunks per ks-group (3 groups x 30 = 90)
#define PSTR 129

typedef _Float16 half8v __attribute__((ext_vector_type(8)));
typedef float    f32x4v __attribute__((ext_vector_type(4)));

// ---------------- prep: split W fp32 -> f16 hi/lo, [chunk 90][e 128][k 32] ------
__global__ __launch_bounds__(256)
void prep_w(const float* __restrict__ W, _Float16* __restrict__ whi,
            _Float16* __restrict__ wlo)
{
    const int e = blockIdx.x;
    for (int j = 0; j < 12; ++j) {
        const int k = j * 256 + threadIdx.x;
        if (k >= HID) break;
        const float v = W[(size_t)e * HID + k];
        const _Float16 h = (_Float16)v;
        const _Float16 l = (_Float16)(v - (float)h);
        const size_t idx = (size_t)(k >> 5) * 4096 + e * 32 + (k & 31);
        whi[idx] = h;
        wlo[idx] = l;
    }
}

// asm-forced 16B global load: regs cannot be collapsed/sunk; order = issue order.
#define GLOAD(dst, ptr) \
    asm volatile("global_load_dwordx4 %0, %1, off" : "=v"(dst) : "v"(ptr))
#define GLOAD_O1024(dst, ptr) \
    asm volatile("global_load_dwordx4 %0, %1, off offset:1024" : "=v"(dst) : "v"(ptr))

// ---------------- fused: 12-wave 3-way k-split, 3-chunk epochs, 3 W reg-sets ------
// grid 256 (1 block/CU), 768 thr (12 waves, 3/SIMD). ks = wv>>2 (k-third, 30
// chunks of 32k), wq = wv&3 -> experts [wq*32,+32) x 64 tok.
// R3 lesson: the epoch cost is the vmcnt FIFO coupling — A-loads issued at epoch
// top sat AHEAD of the W sets in the FIFO, so retiring W(b+1) mid-epoch forced
// a full HBM-latency stall on A with ~1 chunk of cover. Fix: THREE W register
// sets. W(b+1),W(b+2) issue at epoch top BEFORE A; W(b+3) issues after chunk
// b's MFMAs (its set is read until then); A issues LAST (newest in FIFO).
// Waits become: c0 = none (set resident), c1 = VMC(14) (W(b+1) only),
// c2 = VMC(10) (W(b+2) only), epoch end = VMC(0) retiring A after a FULL
// epoch of flight, right before CONVA. One lgkmcnt(0)+s_barrier per epoch.
__global__ __launch_bounds__(768, 3)
void fused_router(const float* __restrict__ A, const _Float16* __restrict__ whi,
                  const _Float16* __restrict__ wlo, const float* __restrict__ bias,
                  float* __restrict__ scores, float* __restrict__ idxOut,
                  float* __restrict__ counts)
{
    // ring: [ks 3][slot 6][h 2][64 tok][32 k f16] = 3*6*8192 = 147456 B
    __shared__ __align__(16) char smem[147456];
    __shared__ float sval[TOKB][4];
    __shared__ int   sidx[TOKB][4];
    __shared__ int   hist[NE];

#define SWZ(tok) ((((tok) >> 1) & 3) << 4)

    const int tid  = threadIdx.x;
    const int lane = tid & 63;
    const int wv   = __builtin_amdgcn_readfirstlane(tid >> 6);   // 0..11
    const int ks   = wv >> 2;        // k-third 0..2
    const int wq   = wv & 3;         // expert group 0..3
    const int lg   = lane >> 4;      // k-quarter 0..3
    const int lr   = lane & 15;
    const int tokBase = blockIdx.x * TOKB;
    const int hbeg = ks * NCHG;      // first global chunk of this k-third

    // W per-lane fragment base (m=0): e = wq*32 + lr, k-off lg*8.
    // m=1 adds 16 experts * 32 halves = 1024 B -> offset:1024 immediate.
    const _Float16* wHp0 = whi + (size_t)((wq * 32 + lr) * 32 + lg * 8);
    const _Float16* wLp0 = wlo + (size_t)((wq * 32 + lr) * 32 + lg * 8);

    // A producer: ks-group's 256 threads stage 64 tok x 32 k per chunk;
    // thread -> (tok, 8-float k-part): 2 dwordx4 per chunk.
    const int gid   = tid & 255;
    const int ptok  = gid >> 2;
    const int ppart = gid & 3;
    const float* aSrc = A + (size_t)(tokBase + ptok) * HID + ppart * 8;
    const int aWr = ptok * 64 + ((ppart * 16) ^ SWZ(ptok));   // swizzled byte off

    // A consumer byte offsets: token n*16+lr, k-quarter lg (same swizzle)
    int aRd[4];
#pragma unroll
    for (int n = 0; n < 4; ++n) {
        const int tok = n * 16 + lr;
        aRd[n] = tok * 64 + ((lg * 16) ^ SWZ(tok));
    }

    // W set: [m*2 + hl] -> 4 half8v = 16 VGPR forced
#define WISSUE(SET, ch) do {                                                   \
    const _Float16* hp_ = wHp0 + (size_t)(ch) * 4096;                          \
    const _Float16* lp_ = wLp0 + (size_t)(ch) * 4096;                          \
    GLOAD(SET[0], hp_);                                                        \
    GLOAD(SET[1], lp_);                                                        \
    GLOAD_O1024(SET[2], hp_);                                                  \
    GLOAD_O1024(SET[3], lp_);                                                  \
} while (0)

    // convert one chunk's A regs (2 float4) -> hi/lo half8, write ring slot
#define CONVA1(AX, AY, SLOT) do {                                              \
    const _Float16 h0=(_Float16)AX.x, h1=(_Float16)AX.y,                       \
                   h2=(_Float16)AX.z, h3=(_Float16)AX.w;                       \
    const _Float16 h4=(_Float16)AY.x, h5=(_Float16)AY.y,                       \
                   h6=(_Float16)AY.z, h7=(_Float16)AY.w;                       \
    const half8v hh = {h0,h1,h2,h3,h4,h5,h6,h7};                               \
    const half8v ll = {(_Float16)(AX.x-(float)h0),(_Float16)(AX.y-(float)h1),  \
                       (_Float16)(AX.z-(float)h2),(_Float16)(AX.w-(float)h3),  \
                       (_Float16)(AY.x-(float)h4),(_Float16)(AY.y-(float)h5),  \
                       (_Float16)(AY.z-(float)h6),(_Float16)(AY.w-(float)h7)}; \
    char* wb_ = smem + ks * 49152 + (SLOT) * 8192 + aWr;                       \
    *reinterpret_cast<half8v*>(wb_)        = hh;                               \
    *reinterpret_cast<half8v*>(wb_ + 4096) = ll;                               \
} while (0)

    // consume one chunk from ring slot with W register set
#define CCHUNK(SLOT, SET) do {                                                 \
    const char* b0_ = smem + ks * 49152 + (SLOT) * 8192;                       \
    _Pragma("unroll")                                                          \
    for (int n = 0; n < 4; ++n) {                                              \
        const half8v ah = *reinterpret_cast<const half8v*>(b0_ + aRd[n]);      \
        const half8v al = *reinterpret_cast<const half8v*>(b0_ + 4096 + aRd[n]);\
        _Pragma("unroll")                                                      \
        for (int m = 0; m < 2; ++m) {                                          \
            acc[m][n] = __builtin_amdgcn_mfma_f32_16x16x32_f16(                \
                SET[m * 2 + 0], ah, acc[m][n], 0, 0, 0);                       \
            acc[m][n] = __builtin_amdgcn_mfma_f32_16x16x32_f16(                \
                SET[m * 2 + 1], ah, acc[m][n], 0, 0, 0);                       \
            acc[m][n] = __builtin_amdgcn_mfma_f32_16x16x32_f16(                \
                SET[m * 2 + 0], al, acc[m][n], 0, 0, 0);                       \
        }                                                                      \
    }                                                                          \
} while (0)

#define VMC(n) do {                                                            \
    asm volatile("s_waitcnt vmcnt(" #n ")" ::: "memory");                      \
    __builtin_amdgcn_sched_barrier(0);                                         \
} while (0)

    f32x4v acc[2][4];
#pragma unroll
    for (int m = 0; m < 2; ++m)
#pragma unroll
        for (int n = 0; n < 4; ++n) acc[m][n] = (f32x4v)0.f;

    half8v wS0[4], wS1[4], wS2[4];
    float4 aR0, aR1, aR2, aR3, aR4, aR5;

    // stage A-group (3 chunks starting at group-local chunk B_) into aR0..aR5
#define ASTAGE(B_) do {                                                        \
    const float* p_ = aSrc + (size_t)(hbeg + (B_)) * BK;                       \
    GLOAD(aR0, p_);      GLOAD(aR1, p_ + 4);                                   \
    GLOAD(aR2, p_ + 32); GLOAD(aR3, p_ + 36);                                  \
    GLOAD(aR4, p_ + 64); GLOAD(aR5, p_ + 68);                                  \
} while (0)

    // EPOCH(E, CS, PS, STAGE, LAST): consume chunks 3E..3E+2 (slots CS..CS+2)
    // with sets S0/S1/S2 (no rotation: Sj always holds chunk = j mod 3).
    // S1,S2 issue at top BEFORE A; S0(b+3) issues after c0's MFMAs (its regs
    // are read until then -> no in-flight clobber); A issues last (newest).
#define EPOCH(E, CS, PS, STAGE, LAST) do {                                     \
    const int b_ = 3 * (E);                                                    \
    WISSUE(wS1, hbeg + b_ + 1);                                                \
    WISSUE(wS2, hbeg + b_ + 2);                                                \
    if (STAGE) ASTAGE(b_ + 3);                                                 \
    __builtin_amdgcn_sched_barrier(0);                                         \
    CCHUNK((CS) + 0, wS0);                                                     \
    __builtin_amdgcn_sched_barrier(0);                                         \
    if (!(LAST)) { WISSUE(wS0, hbeg + b_ + 3); }                               \
    __builtin_amdgcn_sched_barrier(0);                                         \
    if (LAST) VMC(4); else VMC(14);                                            \
    CCHUNK((CS) + 1, wS1);                                                     \
    __builtin_amdgcn_sched_barrier(0);                                         \
    if (LAST) VMC(0); else VMC(10);                                            \
    CCHUNK((CS) + 2, wS2);                                                     \
    if (STAGE) {                                                               \
        VMC(0);                                                                \
        CONVA1(aR0, aR1, (PS) + 0);                                            \
        CONVA1(aR2, aR3, (PS) + 1);                                            \
        CONVA1(aR4, aR5, (PS) + 2);                                            \
        asm volatile("s_waitcnt lgkmcnt(0)" ::: "memory");                     \
        __builtin_amdgcn_sched_barrier(0);                                     \
        __builtin_amdgcn_s_barrier();                                          \
        __builtin_amdgcn_sched_barrier(0);                                     \
    }                                                                          \
} while (0)

    // prologue: A-group(0) + W(chunk 0)->wS0; drain; CONVA slots 0..2; publish.
    ASTAGE(0);
    WISSUE(wS0, hbeg + 0);
    VMC(0);
    CONVA1(aR0, aR1, 0);
    CONVA1(aR2, aR3, 1);
    CONVA1(aR4, aR5, 2);
    asm volatile("s_waitcnt lgkmcnt(0)" ::: "memory");
    __builtin_amdgcn_sched_barrier(0);
    __builtin_amdgcn_s_barrier();
    __builtin_amdgcn_sched_barrier(0);

    // epochs 0..7 (paired even/odd), 8 (even, staging), 9 (odd, final)
#pragma unroll 1
    for (int e = 0; e < 8; e += 2) {
        EPOCH(e,     0, 3, 1, 0);
        EPOCH(e + 1, 3, 0, 1, 0);
    }
    EPOCH(8, 0, 3, 1, 0);
    EPOCH(9, 3, 0, 0, 1);

    __syncthreads();   // all ring reads done before epilogue overlay

    // ---------------- epilogue: deterministic 3-way reduction ----------------
    float* P1   = (float*)(smem);            // 64*129*4 = 33024 B (overlay)
    float* P2   = (float*)(smem + 33024);    // 33024 B
    float* cval = (float*)(smem + 66048);    // 64*33*4 = 8448 B
    int*   cidx = (int*)(smem + 74496);      // 8448 B

    if (tid < NE) hist[tid] = 0;

    // ks=1/2 partials -> LDS
    if (ks == 1 || ks == 2) {
        float* P = (ks == 1) ? P1 : P2;
#pragma unroll
        for (int m = 0; m < 2; ++m)
#pragma unroll
            for (int n = 0; n < 4; ++n)
#pragma unroll
                for (int r = 0; r < 4; ++r) {
                    const int e = wq * 32 + m * 16 + lg * 4 + r;
                    const int t = n * 16 + lr;
                    P[t * PSTR + e] = acc[m][n][r];
                }
    }
    __syncthreads();

    // ks=0 combines in fixed order -> logits in P1
    if (ks == 0) {
#pragma unroll
        for (int m = 0; m < 2; ++m)
#pragma unroll
            for (int n = 0; n < 4; ++n)
#pragma unroll
                for (int r = 0; r < 4; ++r) {
                    const int e = wq * 32 + m * 16 + lg * 4 + r;
                    const int t = n * 16 + lr;
                    const int off = t * PSTR + e;
                    P1[off] = ((acc[m][n][r] + P1[off]) + P2[off]) + bias[e];
                }
    }
    __syncthreads();

    // top-4 candidates: 64 tok x 8 groups of 16 experts (threads 0..511)
    if (tid < 512) {
        const int t = tid & 63, g = tid >> 6;
        float v0 = -1e30f, v1 = -1e30f, v2 = -1e30f, v3 = -1e30f;
        int   i0 = 0, i1 = 0, i2 = 0, i3 = 0;
        const int e0 = g * 16;
#pragma unroll 4
        for (int i = 0; i < 16; ++i) {
            const int e = e0 + i;
            const float v = P1[t * PSTR + e];
            if (v > v3) {
                if (v > v2) {
                    v3 = v2; i3 = i2;
                    if (v > v1) {
                        v2 = v1; i2 = i1;
                        if (v > v0) { v1 = v0; i1 = i0; v0 = v; i0 = e; }
                        else        { v1 = v;  i1 = e; }
                    } else { v2 = v; i2 = e; }
                } else { v3 = v; i3 = e; }
            }
        }
        cval[t * 33 + g * 4 + 0] = v0; cidx[t * 33 + g * 4 + 0] = i0;
        cval[t * 33 + g * 4 + 1] = v1; cidx[t * 33 + g * 4 + 1] = i1;
        cval[t * 33 + g * 4 + 2] = v2; cidx[t * 33 + g * 4 + 2] = i2;
        cval[t * 33 + g * 4 + 3] = v3; cidx[t * 33 + g * 4 + 3] = i3;
    }
    __syncthreads();

    if (tid < TOKB) {
        const int t = tid;
        float m0 = -1e30f, m1 = -1e30f, m2 = -1e30f, m3 = -1e30f;
        int   j0 = 0, j1 = 0, j2 = 0, j3 = 0;
#pragma unroll
        for (int q = 0; q < 32; ++q) {   // group-major, ascending e within group
            const float v = cval[t * 33 + q];
            const int   e = cidx[t * 33 + q];
            if (v > m3) {
                if (v > m2) {
                    m3 = m2; j3 = j2;
                    if (v > m1) {
                        m2 = m1; j2 = j1;
                        if (v > m0) { m1 = m0; j1 = j0; m0 = v; j0 = e; }
                        else        { m1 = v;  j1 = e; }
                    } else { m2 = v; j2 = e; }
                } else { m3 = v; j3 = e; }
            }
        }
        const float x1 = expf(m1 - m0), x2 = expf(m2 - m0), x3 = expf(m3 - m0);
        const float inv = 1.f / (1.f + x1 + x2 + x3);
        sval[t][0] = inv;      sidx[t][0] = j0;
        sval[t][1] = x1 * inv; sidx[t][1] = j1;
        sval[t][2] = x2 * inv; sidx[t][2] = j2;
        sval[t][3] = x3 * inv; sidx[t][3] = j3;
        atomicAdd(&hist[j0], 1); atomicAdd(&hist[j1], 1);
        atomicAdd(&hist[j2], 1); atomicAdd(&hist[j3], 1);
    }
    __syncthreads();

    // dense score scatter: 64 tok x 128 exp = 8192 floats, coalesced
    const size_t sBase = (size_t)blockIdx.x * TOKB * NE;
#pragma unroll 4
    for (int it = 0; it < 11; ++it) {
        const int flat = it * 768 + tid;
        if (flat < TOKB * NE) {
            const int t = flat >> 7, e = flat & 127;
            float val = 0.f;
            val = (e == sidx[t][0]) ? sval[t][0] : val;
            val = (e == sidx[t][1]) ? sval[t][1] : val;
            val = (e == sidx[t][2]) ? sval[t][2] : val;
            val = (e == sidx[t][3]) ? sval[t][3] : val;
            scores[sBase + flat] = val;
        }
    }
    // indices as float32: 256 per block
    if (tid < TOKB * 4)
        idxOut[(size_t)blockIdx.x * TOKB * 4 + tid] =
            (float)sidx[tid >> 2][tid & 3];
    if (tid < NE) {
        const int c = hist[tid];
        if (c) atomicAdd(&counts[tid], (float)c);
    }
#undef SWZ
#undef WISSUE
#undef CONVA1
#undef CCHUNK
#undef VMC
#undef ASTAGE
#undef EPOCH
}

extern "C" void kernel_launch(void* const* d_in, const int* in_sizes, int n_in,
                              void* d_out, int out_size, void* d_ws, size_t ws_size,
                              hipStream_t stream) {
    const float* A = (const float*)d_in[0];   // hidden_states [T, 2880]
    const float* W = (const float*)d_in[1];   // weight [128, 2880]
    const float* B = (const float*)d_in[2];   // bias [128]
    const int T = in_sizes[0] / HID;          // 16384

    float* out = (float*)d_out;
    float* scores = out;                          // [T,128]
    float* idxOut = out + (size_t)T * NE;         // [T,4] as float
    float* counts = idxOut + (size_t)T * 4;       // [128] as float

    _Float16* whi = (_Float16*)d_ws;              // [90][128][32] halves
    _Float16* wlo = whi + (size_t)NE * HID;

    hipMemsetAsync(counts, 0, NE * sizeof(float), stream);

    hipLaunchKernelGGL(prep_w, dim3(NE), dim3(256), 0, stream, W, whi, wlo);
    hipLaunchKernelGGL(fused_router, dim3(T / TOKB), dim3(768), 0, stream,
                       A, whi, wlo, B, scores, idxOut, counts);
}